// Round 9
// baseline (381.724 us; speedup 1.0000x reference)
//
#include <hip/hip_runtime.h>

#define BM 128
#define BN 128
#define BKH 32   // K-half; one barrier pair covers 2 halves (BK=64)

typedef __bf16 bf16x8 __attribute__((ext_vector_type(8)));
typedef __bf16 bf16x4 __attribute__((ext_vector_type(4)));
typedef float f32x4 __attribute__((ext_vector_type(4)));
typedef __bf16 bf16_t;

__device__ __forceinline__ void gl_lds16(const void* g, void* l) {
    __builtin_amdgcn_global_load_lds(
        (const __attribute__((address_space(1))) void*)g,
        (__attribute__((address_space(3))) void*)l, 16, 0, 0);
}

// fp32 -> bf16 conversion for hid + 4 weight matrices in ONE launch.
__global__ __launch_bounds__(256)
void cvt_all_kernel(const float* __restrict__ hid,
                    const float* __restrict__ w0, const float* __restrict__ w1,
                    const float* __restrict__ w2, const float* __restrict__ w3,
                    bf16_t* __restrict__ hidb, bf16_t* __restrict__ wb)
{
    const int bid = blockIdx.x;
    const float* src;
    bf16_t* dst;
    size_t off;
    if (bid < 8192) {
        src = hid; dst = hidb; off = (size_t)bid * 1024;
    } else {
        const int i = (bid - 8192) >> 10;
        src = (i == 0) ? w0 : (i == 1) ? w1 : (i == 2) ? w2 : w3;
        dst = wb + (size_t)i * 1024 * 1024;
        off = (size_t)((bid - 8192) & 1023) * 1024;
    }
    const size_t idx = off + threadIdx.x * 4;
    const float4 v = *(const float4*)(src + idx);
    bf16x4 o;
    o[0] = (__bf16)v.x; o[1] = (__bf16)v.y;
    o[2] = (__bf16)v.z; o[3] = (__bf16)v.w;
    *(bf16x4*)(dst + idx) = o;
}

// Generic NT GEMM: C[m,n] = sum_k A[m,k] * Bw[n,k]  (+ epilogue per MODE)
// MODE 0: QKV fused over z: z=0 -> Wq/bq; z=1 -> Wk/bk; z=2 -> Wv/bv transposed
//         (B = 2 MB/layer fits per-XCD L2 — measured best; N=3072 merge thrashes)
// MODE 3: plain bf16 store, batched z                  [scores, PV]
// MODE 4: + bias[n] + resid[m,n] (bf16), bf16 out      [out-proj + residual]
// SWIZ=1: 1D x-grid, grouped decode (GM=8): same-XCD blocks share one A-tile.
// SWIZ=0: plain 2D (blockIdx.x = n-tile, blockIdx.y = m-tile).
template <int MODE, int SWIZ>
__global__ __launch_bounds__(256)
void gemm_bt(const bf16_t* __restrict__ A, const bf16_t* __restrict__ Bw,
             const float* __restrict__ bias, const float* __restrict__ bias2,
             const float* __restrict__ bias3,
             bf16_t* __restrict__ C, bf16_t* __restrict__ C2,
             int M, int N, int K,
             long long sAz, long long sBz, long long sCz,
             const bf16_t* __restrict__ resid,
             int Sdim, int DHdim)
{
    const int bz = blockIdx.z;
    const float* bi = bias;
    if (MODE == 0) {
        Bw += (long long)bz * N * K;        // Wq | Wk | Wv contiguous
        bi = (bz == 0) ? bias : (bz == 1 ? bias2 : bias3);
        if (bz < 2) C += (long long)bz * sCz;
    } else {
        A += (long long)bz * sAz;
        Bw += (long long)bz * sBz;
        C += (long long)bz * sCz;
    }

    int m0, n0;
    if (SWIZ) {
        const int num_n = N / BN;
        const int pid = blockIdx.x;
        const int group = 8 * num_n;         // 8 m-tiles per group
        const int g = pid / group;
        m0 = (g * 8 + (pid % 8)) * BM;
        n0 = ((pid % group) / 8) * BN;
    } else {
        m0 = blockIdx.y * BM;
        n0 = blockIdx.x * BN;
    }
    const int tid = threadIdx.x;
    const int w = tid >> 6;          // wave id 0..3
    const int lane = tid & 63;
    const int wr = w >> 1;           // wave row (2x2 wave grid, 64x64 each)
    const int wc = w & 1;
    const int srow = lane >> 2;      // staging: row within 16-row slice
    const int scol = (lane & 3) * 8; // staging: bf16 col offset (16B chunks)
    const int frow = lane & 15;      // fragment m/n index
    const int fk = (lane >> 4) * 8;  // fragment k base

    __shared__ bf16_t smem[4 * BM * BKH];   // 32 KB: A0 | A1 | B0 | B1
    bf16_t* A0 = smem;
    bf16_t* A1 = smem + BM * BKH;
    bf16_t* B0 = smem + 2 * BM * BKH;
    bf16_t* B1 = smem + 3 * BM * BKH;

    f32x4 acc[4][4];
#pragma unroll
    for (int i = 0; i < 4; ++i)
#pragma unroll
        for (int j = 0; j < 4; ++j) acc[i][j] = (f32x4)0.0f;

    for (int k0 = 0; k0 < K; k0 += 2 * BKH) {
#pragma unroll
        for (int i = 0; i < 2; ++i) {
            const int r = i * 64 + w * 16;
            const bf16_t* ga = A + (size_t)(m0 + r + srow) * K + (k0 + scol);
            const bf16_t* gb = Bw + (size_t)(n0 + r + srow) * K + (k0 + scol);
            gl_lds16(ga,        &A0[r * BKH]);
            gl_lds16(ga + BKH,  &A1[r * BKH]);
            gl_lds16(gb,        &B0[r * BKH]);
            gl_lds16(gb + BKH,  &B1[r * BKH]);
        }
        __syncthreads();
#pragma unroll
        for (int h = 0; h < 2; ++h) {
            const bf16_t* Ah = h ? A1 : A0;
            const bf16_t* Bh = h ? B1 : B0;
            bf16x8 af[4], bfv[4];
#pragma unroll
            for (int t = 0; t < 4; ++t) {
                af[t]  = *(const bf16x8*)&Ah[(wr * 64 + t * 16 + frow) * BKH + fk];
                bfv[t] = *(const bf16x8*)&Bh[(wc * 64 + t * 16 + frow) * BKH + fk];
            }
#pragma unroll
            for (int mt = 0; mt < 4; ++mt)
#pragma unroll
                for (int nt = 0; nt < 4; ++nt)
                    acc[mt][nt] = __builtin_amdgcn_mfma_f32_16x16x32_bf16(
                        af[mt], bfv[nt], acc[mt][nt], 0, 0, 0);
        }
        __syncthreads();
    }
    // After the final __syncthreads all LDS reads are drained; smem reusable.

    // C/D layout: col = lane&15, row = (lane>>4)*4 + reg
    const int crow = (lane >> 4) * 4;
    const int ccol = lane & 15;

    if (MODE == 0 && bz == 2) {
        // V projection: transposed store vT[b][n][s]
#pragma unroll
        for (int mt = 0; mt < 4; ++mt) {
            const int mb = m0 + wr * 64 + mt * 16 + crow;
#pragma unroll
            for (int nt = 0; nt < 4; ++nt) {
                const int n = n0 + wc * 64 + nt * 16 + ccol;
                const float bv = bi[n];
                const int b = mb >> 11;      // S = 2048 tokens per batch
                const int s = mb & 2047;
                union { ushort4 u; bf16_t h[4]; } pk;
#pragma unroll
                for (int r = 0; r < 4; ++r) pk.h[r] = (__bf16)(acc[mt][nt][r] + bv);
                *(ushort4*)&C2[(size_t)b * DHdim * Sdim + (size_t)n * Sdim + s] = pk.u;
            }
        }
        return;
    }

    // ---- transpose epilogue ----
    bf16_t* tw = smem + w * (16 * 72);
    const int r0 = lane >> 3;            // 0..7 : row within 16-slice
    const int cseg = (lane & 7) * 8;     // 8-col segment base

    float bv[4];
    if (MODE == 0 || MODE == 4) {
#pragma unroll
        for (int nt = 0; nt < 4; ++nt)
            bv[nt] = bi[n0 + wc * 64 + nt * 16 + ccol];
    }

#pragma unroll
    for (int mt = 0; mt < 4; ++mt) {
#pragma unroll
        for (int nt = 0; nt < 4; ++nt) {
            const float badd = (MODE == 0 || MODE == 4) ? bv[nt] : 0.0f;
#pragma unroll
            for (int r = 0; r < 4; ++r)
                tw[(crow + r) * 72 + nt * 16 + ccol] = (__bf16)(acc[mt][nt][r] + badd);
        }
        bf16x8 va = *(const bf16x8*)&tw[r0 * 72 + cseg];
        bf16x8 vb = *(const bf16x8*)&tw[(r0 + 8) * 72 + cseg];

        const int gm_a = m0 + wr * 64 + mt * 16 + r0;
        const int gm_b = gm_a + 8;
        const int gn = n0 + wc * 64 + cseg;

        if (MODE == 0 || MODE == 3) {
            *(bf16x8*)&C[(size_t)gm_a * N + gn] = va;
            *(bf16x8*)&C[(size_t)gm_b * N + gn] = vb;
        } else {  // MODE 4: + residual (bf16), bf16 out
            const bf16x8 xa = *(const bf16x8*)&resid[(size_t)gm_a * N + gn];
            const bf16x8 xb = *(const bf16x8*)&resid[(size_t)gm_b * N + gn];
            bf16x8 oa, ob;
#pragma unroll
            for (int j = 0; j < 8; ++j) {
                oa[j] = (__bf16)((float)va[j] + (float)xa[j]);
                ob[j] = (__bf16)((float)vb[j] + (float)xb[j]);
            }
            *(bf16x8*)&C[(size_t)gm_a * N + gn] = oa;
            *(bf16x8*)&C[(size_t)gm_b * N + gn] = ob;
        }
    }
}

// Fused softmax, 2 rows per 256-thread block (128 threads/row, 16 elem/thread).
// Per row: d1 = q[row]·de[1]; v = s/32 + mask + (rel==1 ? d1/32 : 0);
// max/exp/sum; write probs bf16.
__global__ __launch_bounds__(256)
void softmax_kernel(bf16_t* __restrict__ sc, const int* __restrict__ rel,
                    const bf16_t* __restrict__ q, const float* __restrict__ de,
                    const float* __restrict__ mask)
{
    constexpr int S = 2048, H = 1024;
    const int tid = threadIdx.x;
    const int half = tid >> 7;           // 0/1: which row of the pair
    const int t = tid & 127;
    const int row = blockIdx.x * 2 + half;
    const int b = row >> 11;             // 2048 rows per batch
    const int w = tid >> 6, lane = tid & 63;
    __shared__ float rd1[4], rmax[4], rsum[4];

    // ---- d1 = q[row,:] . de[1,:]  (8 elems/thread over 128 threads) ----
    const bf16x8 q8 = *(const bf16x8*)(q + (size_t)row * H + t * 8);
    const float4 e0 = *(const float4*)(de + H + t * 8);
    const float4 e1 = *(const float4*)(de + H + t * 8 + 4);
    float pd = (float)q8[0] * e0.x + (float)q8[1] * e0.y
             + (float)q8[2] * e0.z + (float)q8[3] * e0.w
             + (float)q8[4] * e1.x + (float)q8[5] * e1.y
             + (float)q8[6] * e1.z + (float)q8[7] * e1.w;
#pragma unroll
    for (int off = 32; off; off >>= 1) pd += __shfl_xor(pd, off, 64);
    if (lane == 0) rd1[w] = pd;
    __syncthreads();
    const float d1s = (rd1[half * 2] + rd1[half * 2 + 1]) * 0.03125f;

    // ---- main: 16 consecutive cols per thread ----
    bf16_t* p = sc + (size_t)row * S + t * 16;
    const bf16x8 x0 = *(const bf16x8*)p;
    const bf16x8 x1 = *(const bf16x8*)(p + 8);
    const size_t rbase = (size_t)row * S + t * 16;
    const int4 r0 = *(const int4*)&rel[rbase];
    const int4 r1 = *(const int4*)&rel[rbase + 4];
    const int4 r2 = *(const int4*)&rel[rbase + 8];
    const int4 r3 = *(const int4*)&rel[rbase + 12];
    const size_t mbase = (size_t)b * S + t * 16;
    const float4 m0 = *(const float4*)&mask[mbase];
    const float4 m1 = *(const float4*)&mask[mbase + 4];
    const float4 m2 = *(const float4*)&mask[mbase + 8];
    const float4 m3 = *(const float4*)&mask[mbase + 12];
    const int rls[16] = {r0.x, r0.y, r0.z, r0.w, r1.x, r1.y, r1.z, r1.w,
                         r2.x, r2.y, r2.z, r2.w, r3.x, r3.y, r3.z, r3.w};
    const float mks[16] = {m0.x, m0.y, m0.z, m0.w, m1.x, m1.y, m1.z, m1.w,
                           m2.x, m2.y, m2.z, m2.w, m3.x, m3.y, m3.z, m3.w};
    float v[16];
    float mx = -1e30f;
#pragma unroll
    for (int j = 0; j < 16; ++j) {
        const float s = (float)(j < 8 ? x0[j] : x1[j - 8]);
        v[j] = s * 0.03125f + mks[j] + (rls[j] == 1 ? d1s : 0.0f);
        mx = fmaxf(mx, v[j]);
    }
#pragma unroll
    for (int off = 32; off; off >>= 1) mx = fmaxf(mx, __shfl_xor(mx, off, 64));
    if (lane == 0) rmax[w] = mx;
    __syncthreads();
    mx = fmaxf(rmax[half * 2], rmax[half * 2 + 1]);
    float sum = 0.0f;
#pragma unroll
    for (int j = 0; j < 16; ++j) { v[j] = __expf(v[j] - mx); sum += v[j]; }
#pragma unroll
    for (int off = 32; off; off >>= 1) sum += __shfl_xor(sum, off, 64);
    if (lane == 0) rsum[w] = sum;
    __syncthreads();
    sum = rsum[half * 2] + rsum[half * 2 + 1];
    const float inv = 1.0f / sum;
    bf16x8 o0, o1;
#pragma unroll
    for (int j = 0; j < 8; ++j) {
        o0[j] = (__bf16)(v[j] * inv);
        o1[j] = (__bf16)(v[j + 8] * inv);
    }
    *(bf16x8*)p = o0;
    *(bf16x8*)(p + 8) = o1;
}

// LayerNorm over H=1024, bf16 in / fp32 out. 2 rows per 256-thr block.
__global__ __launch_bounds__(256)
void ln_kernel(const bf16_t* __restrict__ x, const float* __restrict__ gamma,
               const float* __restrict__ beta, float* __restrict__ out)
{
    const int H = 1024;
    const int tid = threadIdx.x;
    const int half = tid >> 7;
    const int t7 = tid & 127;
    const size_t row = (size_t)blockIdx.x * 2 + half;
    const int w = tid >> 6, lane = tid & 63;
    const bf16x8 xv = *(const bf16x8*)(x + row * H + t7 * 8);
    float v[8], s = 0.0f, s2 = 0.0f;
#pragma unroll
    for (int j = 0; j < 8; ++j) {
        v[j] = (float)xv[j];
        s += v[j]; s2 += v[j] * v[j];
    }
#pragma unroll
    for (int off = 32; off; off >>= 1) {
        s += __shfl_xor(s, off, 64);
        s2 += __shfl_xor(s2, off, 64);
    }
    __shared__ float rs[4], rs2[4];
    if (lane == 0) { rs[w] = s; rs2[w] = s2; }
    __syncthreads();
    s  = rs[half * 2] + rs[half * 2 + 1];
    s2 = rs2[half * 2] + rs2[half * 2 + 1];
    const float mu  = s * (1.0f / H);
    const float var = s2 * (1.0f / H) - mu * mu;
    const float inv = rsqrtf(var + 1e-12f);
    const int c = t7 * 8;
    float4 o0, o1;
    o0.x = (v[0] - mu) * inv * gamma[c + 0] + beta[c + 0];
    o0.y = (v[1] - mu) * inv * gamma[c + 1] + beta[c + 1];
    o0.z = (v[2] - mu) * inv * gamma[c + 2] + beta[c + 2];
    o0.w = (v[3] - mu) * inv * gamma[c + 3] + beta[c + 3];
    o1.x = (v[4] - mu) * inv * gamma[c + 4] + beta[c + 4];
    o1.y = (v[5] - mu) * inv * gamma[c + 5] + beta[c + 5];
    o1.z = (v[6] - mu) * inv * gamma[c + 6] + beta[c + 6];
    o1.w = (v[7] - mu) * inv * gamma[c + 7] + beta[c + 7];
    *(float4*)(out + row * H + c) = o0;
    *(float4*)(out + row * H + c + 4) = o1;
}

extern "C" void kernel_launch(void* const* d_in, const int* in_sizes, int n_in,
                              void* d_out, int out_size, void* d_ws, size_t ws_size,
                              hipStream_t stream)
{
    constexpr int B = 4, S = 2048, H = 1024;
    const float* hid = (const float*)d_in[0];
    const float* am  = (const float*)d_in[1];
    const int*   rel = (const int*)d_in[2];
    const float* Wq  = (const float*)d_in[3];
    const float* bq  = (const float*)d_in[4];
    const float* Wk  = (const float*)d_in[5];
    const float* bk  = (const float*)d_in[6];
    const float* Wv  = (const float*)d_in[7];
    const float* bv  = (const float*)d_in[8];
    const float* de  = (const float*)d_in[9];
    const float* Wo  = (const float*)d_in[10];
    const float* bo  = (const float*)d_in[11];
    const float* lng = (const float*)d_in[12];
    const float* lnb = (const float*)d_in[13];
    float* out = (float*)d_out;

    char* ws = (char*)d_ws;
    const int n_tok = B * S;                               // 8192
    const size_t MB = 1024 * 1024;
    bf16_t* hidb = (bf16_t*)(ws);                          // 16 MB
    bf16_t* Wqb  = (bf16_t*)(ws + 16 * MB);                // 2 MB each; Wq/Wk/Wv/Wo contiguous
    bf16_t* Wob  = (bf16_t*)(ws + 22 * MB);
    bf16_t* qb   = (bf16_t*)(ws + 24 * MB);                // 16 MB
    bf16_t* kb   = (bf16_t*)(ws + 40 * MB);                // 16 MB
    bf16_t* vT   = (bf16_t*)(ws + 56 * MB);                // 16 MB (B, DH, S)
    bf16_t* ctx  = (bf16_t*)(ws + 72 * MB);                // 16 MB
    bf16_t* sc   = (bf16_t*)(ws + 88 * MB);                // 32 MB (B,S,S)
    bf16_t* xb   = (bf16_t*)(ws + 88 * MB);                // 16 MB, ALIASES sc (sc dead after PV)

    const dim3 blk(256);
    // hid + Wq/Wk/Wv/Wo fp32->bf16 in one launch (weights contiguous at Wqb)
    cvt_all_kernel<<<dim3(8192 + 4 * 1024), blk, 0, stream>>>(
        hid, Wq, Wk, Wv, Wo, hidb, Wqb);

    // Q + K + V projections fused over z (B = 2 MB/layer, fits per-XCD L2),
    // GM=8 swizzle: 64 m-tiles x 8 n-tiles per z-layer.
    gemm_bt<0, 1><<<dim3(64 * 8, 1, 3), blk, 0, stream>>>(
        hidb, Wqb, bq, bk, bv, qb, vT, n_tok, H, H,
        0, 0, (long long)n_tok * H,
        nullptr, S, H);
    // scores = q@k^T  (pure GEMM, 2D grid; rel/d1/scale/mask in softmax)
    gemm_bt<3, 0><<<dim3(S / BN, S / BM, B), blk, 0, stream>>>(
        qb, kb, nullptr, nullptr, nullptr, sc, nullptr, S, S, H,
        (long long)S * H, (long long)S * H, (long long)S * S,
        nullptr, S, H);
    softmax_kernel<<<dim3(B * S / 2), blk, 0, stream>>>(sc, rel, qb, de, am);
    // ctx = probs @ v  (2D grid — measured best)
    gemm_bt<3, 0><<<dim3(H / BN, S / BM, B), blk, 0, stream>>>(
        sc, vT, nullptr, nullptr, nullptr, ctx, nullptr, S, H, S,
        (long long)S * S, (long long)H * S, (long long)S * H,
        nullptr, S, H);
    // attn_out = ctx @ Wo^T + bo; x = attn_out + hidden(bf16)  (aliases sc)
    gemm_bt<4, 0><<<dim3(H / BN, n_tok / BM, 1), blk, 0, stream>>>(
        ctx, Wob, bo, nullptr, nullptr, xb, nullptr, n_tok, H, H, 0, 0, 0,
        hidb, S, H);
    ln_kernel<<<dim3(n_tok / 2), blk, 0, stream>>>(xb, lng, lnb, out);
}